// Round 1
// 226.701 us; speedup vs baseline: 1.0268x; 1.0268x over previous
//
#include <hip/hip_runtime.h>

// EnhancedHamiltonianEvolution: out = Hamilton(ql_n, Hamilton(g*x, conj(qr_n)))
// FFT removed: spectral_gate is constant along the transform (time) axis,
// so ifft(fft(x)*g).real == g*x exactly by DFT linearity.
//
// R1 changes vs 231.8us baseline kernel:
//  - grid-stride (2048 blocks x 256): stride is a multiple of 128 work-items,
//    so each thread's feature group f4 is loop-invariant -> all q_left/q_right
//    normalization, conjugation and gate folding hoisted out of the bt loop
//    (removes 2 rsqrtf + ~80 VALU ops per row per thread).
//  - gate folded into the precomputed right-quaternion: c = conj(qr)*rinv*g,
//    mathematically identical ((x*g) ⊗ c == x ⊗ (g*c), scalar assoc).
//  - nontemporal loads/stores: pure streaming (268 MB through 32 MB L2),
//    no reuse -> nt policy avoids L2 write-allocate churn.

constexpr int D_MODEL = 2048;
constexpr int QD      = 512;       // QUAT_DIM
constexpr int NF4     = QD / 4;    // 128 float4 groups per component row

typedef float v4 __attribute__((ext_vector_type(4)));

__global__ __launch_bounds__(256) void quat_rot_kernel(
    const float* __restrict__ x,
    const float* __restrict__ q_left,
    const float* __restrict__ q_right,
    const float* __restrict__ gate,
    float* __restrict__ out,
    int n_bt)
{
    const int tid          = blockIdx.x * blockDim.x + threadIdx.x;
    const int stride_items = gridDim.x * blockDim.x;   // blockDim=256 -> multiple of 128
    const int f4           = tid & (NF4 - 1);          // loop-invariant feature group
    const int f            = f4 << 2;
    const int bt0          = tid >> 7;                 // / NF4
    const int bt_stride    = stride_items >> 7;

    // ---- hoisted per-feature quaternion prep (4 consecutive features) ----
    v4 lw = *(const v4*)(q_left  + 0 * QD + f);
    v4 lx = *(const v4*)(q_left  + 1 * QD + f);
    v4 ly = *(const v4*)(q_left  + 2 * QD + f);
    v4 lz = *(const v4*)(q_left  + 3 * QD + f);
    v4 rw = *(const v4*)(q_right + 0 * QD + f);
    v4 rx = *(const v4*)(q_right + 1 * QD + f);
    v4 ry = *(const v4*)(q_right + 2 * QD + f);
    v4 rz = *(const v4*)(q_right + 3 * QD + f);
    v4 g  = *(const v4*)(gate + f);

    const float eps = 1e-8f;
    v4 ln2 = lw*lw + lx*lx + ly*ly + lz*lz + eps;
    v4 rn2 = rw*rw + rx*rx + ry*ry + rz*rz + eps;
    v4 linv, rinv;
#pragma unroll
    for (int j = 0; j < 4; ++j) {
        linv[j] = rsqrtf(ln2[j]);
        rinv[j] = rsqrtf(rn2[j]);
    }
    // normalized q_left
    lw *= linv; lx *= linv; ly *= linv; lz *= linv;
    // normalized conjugate of q_right, gate folded in
    v4 s  = rinv * g;
    v4 cw =  rw * s;
    v4 cx = -rx * s;
    v4 cy = -ry * s;
    v4 cz = -rz * s;

    // ---- streaming bt loop: load 64B, 2 Hamiltons, store 64B ----
    for (int bt = bt0; bt < n_bt; bt += bt_stride) {
        size_t base = (size_t)bt * D_MODEL + f;
        v4 aw = __builtin_nontemporal_load((const v4*)(x + base + 0 * QD));
        v4 ax = __builtin_nontemporal_load((const v4*)(x + base + 1 * QD));
        v4 ay = __builtin_nontemporal_load((const v4*)(x + base + 2 * QD));
        v4 az = __builtin_nontemporal_load((const v4*)(x + base + 3 * QD));

        // t = a ⊗ c   (x_filt * qr_conj; gate already folded into c)
        v4 tw = aw*cw - ax*cx - ay*cy - az*cz;
        v4 tx = aw*cx + ax*cw + ay*cz - az*cy;
        v4 ty = aw*cy - ax*cz + ay*cw + az*cx;
        v4 tz = aw*cz + ax*cy - ay*cx + az*cw;
        // o = l ⊗ t   (ql * t)
        v4 ow = lw*tw - lx*tx - ly*ty - lz*tz;
        v4 ox = lw*tx + lx*tw + ly*tz - lz*ty;
        v4 oy = lw*ty - lx*tz + ly*tw + lz*tx;
        v4 oz = lw*tz + lx*ty - ly*tx + lz*tw;

        __builtin_nontemporal_store(ow, (v4*)(out + base + 0 * QD));
        __builtin_nontemporal_store(ox, (v4*)(out + base + 1 * QD));
        __builtin_nontemporal_store(oy, (v4*)(out + base + 2 * QD));
        __builtin_nontemporal_store(oz, (v4*)(out + base + 3 * QD));
    }
}

extern "C" void kernel_launch(void* const* d_in, const int* in_sizes, int n_in,
                              void* d_out, int out_size, void* d_ws, size_t ws_size,
                              hipStream_t stream) {
    const float* x      = (const float*)d_in[0];
    const float* q_left = (const float*)d_in[1];
    const float* q_right= (const float*)d_in[2];
    const float* gate   = (const float*)d_in[3];
    float* out          = (float*)d_out;

    int n_bt = in_sizes[0] / D_MODEL;              // B*T = 16384
    long total = (long)n_bt * NF4;                 // work items
    int block = 256;
    long blocks_needed = (total + block - 1) / block;
    int grid = (int)(blocks_needed < 2048 ? blocks_needed : 2048);
    quat_rot_kernel<<<grid, block, 0, stream>>>(x, q_left, q_right, gate, out, n_bt);
}